// Round 6
// baseline (265.648 us; speedup 1.0000x reference)
//
#include <hip/hip_runtime.h>
#include <hip/hip_bf16.h>

// GAT_51788715655952. Counting sort of edges by dst via 2-level bucket sort
// (phase 1: scatter packed (dst,src) into 100 coarse buckets -- ~200B contiguous
// segments per (block,bucket) so line amplification ~1.3x; phase 2: per-bucket
// LDS sort + fully coalesced ssrc writes). Round-5 rocprof: single-phase scatter
// wrote 35MB for a 2.56MB payload (lines ~ blocks x bins) at 46us.
// Per-node wave then does online-softmax weighted sum of ys[src]; edge-linear
// decomposed: agg[i] = deg*(yd[i]+elb) + (sum w_e*ys[src_e])/sum w_e + wsum[i]*elw[64] + b.

#define HID 32
#define NB_SORT 128
#define BUCK_SHIFT 6
#define BUCK_BINS 64
#define BSORT_CAP 20480   // ushort staging entries (40KB LDS); mean bucket ~12.8K

typedef unsigned short ushort_t;
typedef unsigned int uint_t;

// per-block LDS histogram: counts + sum|ea| per dst bin, written as partials.
__global__ void k_part_hist(const int* __restrict__ dst, const float* __restrict__ ea,
                            int* __restrict__ part, float* __restrict__ partw,
                            int E, int nbins, int chunk) {
    extern __shared__ int lds[];                   // nbins ints + nbins floats
    int* hc = lds;
    float* hw = (float*)(lds + nbins);
    for (int i = threadIdx.x; i < nbins; i += blockDim.x) { hc[i] = 0; hw[i] = 0.f; }
    __syncthreads();
    int b = blockIdx.x;
    int lo = b * chunk, hi = min(lo + chunk, E);
    for (int e = lo + threadIdx.x; e < hi; e += blockDim.x) {
        int d = dst[e];
        atomicAdd(&hc[d], 1);                      // LDS atomic
        atomicAdd(&hw[d], fabsf(ea[e]));           // LDS atomic
    }
    __syncthreads();
    for (int i = threadIdx.x; i < nbins; i += blockDim.x) {
        part[b * nbins + i]  = hc[i];
        partw[b * nbins + i] = hw[i];
    }
}

// bin-parallel column reduce: totals[i] = sum_b part[b][i]; wsum[i] = sum_b partw[b][i].
__global__ void k_reduce(const int* __restrict__ part, const float* __restrict__ partw,
                         int* __restrict__ totals, float* __restrict__ wsum,
                         int nbins, int nb) {
    int i = blockIdx.x * blockDim.x + threadIdx.x;
    if (i >= nbins) return;
    int t = 0; float w = 0.f;
    for (int b = 0; b < nb; b++) {
        t += part[b * nbins + i];
        w += partw[b * nbins + i];
    }
    totals[i] = t;
    wsum[i] = w;
}

// single block: exclusive scan of totals[nbins] -> offsets[nbins+1]; zero pool.
__global__ void k_scan_small(const int* __restrict__ totals, int* __restrict__ offsets,
                             float* __restrict__ pool, int nbins, int poolN) {
    __shared__ int wtot[16];
    int t = threadIdx.x;
    int chunk = (nbins + 1023) / 1024;
    int lo = t * chunk, hi = min(lo + chunk, nbins);
    int s = 0;
    for (int i = lo; i < hi; i++) s += totals[i];
    int lane = t & 63, wid = t >> 6;
    int v = s;
    for (int d = 1; d < 64; d <<= 1) { int u = __shfl_up(v, d); if (lane >= d) v += u; }
    if (lane == 63) wtot[wid] = v;
    __syncthreads();
    if (wid == 0) {
        int w = (lane < 16) ? wtot[lane] : 0;
        for (int d = 1; d < 16; d <<= 1) { int u = __shfl_up(w, d); if (lane >= d) w += u; }
        if (lane < 16) wtot[lane] = w;
    }
    __syncthreads();
    int run = (wid > 0 ? wtot[wid - 1] : 0) + (v - s);   // exclusive prefix
    for (int i = lo; i < hi; i++) {
        offsets[i] = run;
        run += totals[i];
    }
    if (lo < nbins && hi == nbins) offsets[nbins] = run;
    if (t < poolN) pool[t] = 0.f;
}

// per-(block,bucket) start cursors: bcur[b][g] = offsets[g*64] + sum_{b'<b} count(b',g).
// one block per bucket; 64 lanes sum the bucket's bins, running prefix over b.
__global__ void k_bcur(const int* __restrict__ part, const int* __restrict__ offsets,
                       int* __restrict__ bcur, int nbins, int nb, int nbuck) {
    int g = blockIdx.x;
    if (g >= nbuck) return;
    int binlo = g << BUCK_SHIFT;
    int nbin = min(BUCK_BINS, nbins - binlo);
    int lane = threadIdx.x;
    int base = offsets[binlo];
    for (int b = 0; b < nb; b++) {
        int v = (lane < nbin) ? part[b * nbins + binlo + lane] : 0;
        #pragma unroll
        for (int mask = 32; mask >= 1; mask >>= 1) v += __shfl_xor(v, mask);
        if (lane == 0) bcur[b * nbuck + g] = base;
        base += v;                                 // identical on all lanes
    }
}

// phase-1 scatter: packed (dst<<16)|src into bucket regions (LDS bucket cursors).
__global__ void k_bscatter(const int* __restrict__ src, const int* __restrict__ dst,
                           const int* __restrict__ bcur, uint_t* __restrict__ ebuf,
                           int E, int nbuck, int chunk) {
    extern __shared__ int cur[];                   // nbuck ints
    int b = blockIdx.x;
    for (int i = threadIdx.x; i < nbuck; i += blockDim.x) cur[i] = bcur[b * nbuck + i];
    __syncthreads();
    int lo = b * chunk, hi = min(lo + chunk, E);
    for (int e = lo + threadIdx.x; e < hi; e += blockDim.x) {
        int d = dst[e];
        int p = atomicAdd(&cur[d >> BUCK_SHIFT], 1);   // LDS atomic
        ebuf[p] = ((uint_t)d << 16) | (uint_t)src[e];
    }
}

// phase-2: per-bucket LDS counting sort; ssrc written fully contiguous.
__global__ void k_bsort(const uint_t* __restrict__ ebuf, const int* __restrict__ offsets,
                        ushort_t* __restrict__ ssrc, int nbins, int nbuck) {
    __shared__ int hist[BUCK_BINS];
    __shared__ int cur[BUCK_BINS];
    extern __shared__ ushort_t sbuf[];             // BSORT_CAP entries
    int g = blockIdx.x;
    if (g >= nbuck) return;
    int binlo = g << BUCK_SHIFT;
    int nbin = min(BUCK_BINS, nbins - binlo);
    int base = offsets[binlo];
    int cnt = offsets[binlo + nbin] - base;
    int t = threadIdx.x;
    if (t < BUCK_BINS) hist[t] = 0;
    __syncthreads();
    for (int i = t; i < cnt; i += blockDim.x) {
        int dl = (int)(ebuf[base + i] >> 16) - binlo;
        atomicAdd(&hist[dl], 1);
    }
    __syncthreads();
    if (t < BUCK_BINS) {                           // wave 0: exclusive scan of 64 bins
        int v = hist[t];
        int p = v;
        #pragma unroll
        for (int d = 1; d < 64; d <<= 1) { int u = __shfl_up(p, d); if (t >= d) p += u; }
        cur[t] = p - v;
    }
    __syncthreads();
    if (cnt <= BSORT_CAP) {
        for (int i = t; i < cnt; i += blockDim.x) {
            uint_t v = ebuf[base + i];
            int dl = (int)(v >> 16) - binlo;
            int p = atomicAdd(&cur[dl], 1);        // LDS atomic
            sbuf[p] = (ushort_t)(v & 0xFFFFu);     // LDS staging
        }
        __syncthreads();
        for (int i = t; i < cnt; i += blockDim.x)  // coalesced contiguous write
            ssrc[base + i] = sbuf[i];
    } else {                                       // fallback (never expected)
        for (int i = t; i < cnt; i += blockDim.x) {
            uint_t v = ebuf[base + i];
            int dl = (int)(v >> 16) - binlo;
            int p = atomicAdd(&cur[dl], 1);
            ssrc[base + p] = (ushort_t)(v & 0xFFFFu);
        }
    }
}

// shared epilogue: given xp (lane l of a 32-lane group holds xp[row][l]), compute
// als/ald (group reduce) and ys/yd (group broadcast matmul vs elw).
__device__ __forceinline__ void node_epilogue(float xp, int r, int l,
        const float* __restrict__ asrc, const float* __restrict__ adst,
        const float* __restrict__ elw,
        float* __restrict__ ys, float* __restrict__ yd,
        float* __restrict__ als, float* __restrict__ ald) {
    float ps = xp * asrc[l], pd = xp * adst[l];
    #pragma unroll
    for (int mask = 16; mask >= 1; mask >>= 1) {
        ps += __shfl_xor(ps, mask);
        pd += __shfl_xor(pd, mask);
    }
    if (l == 0) { als[r] = ps; ald[r] = pd; }
    int gbase = threadIdx.x & 32;   // group base lane within the 64-wide wave
    float yss = 0.f, ydd = 0.f;
    #pragma unroll
    for (int k = 0; k < HID; k++) {
        float xk = __shfl(xp, gbase + k);
        yss = fmaf(xk, elw[(HID + k) * HID + l], yss);
        ydd = fmaf(xk, elw[k * HID + l], ydd);
    }
    ys[r * HID + l] = yss;
    yd[r * HID + l] = ydd;
}

// block 1 prep: xp = x @ w1 (K=200, w1 staged in LDS), fused epilogue.
__global__ void k_b1prep(const float* __restrict__ x, const float* __restrict__ w1,
                         const float* __restrict__ asrc, const float* __restrict__ adst,
                         const float* __restrict__ elw,
                         float* __restrict__ ys, float* __restrict__ yd,
                         float* __restrict__ als, float* __restrict__ ald,
                         int n, int K) {
    extern __shared__ float wlds[];                 // K*32 floats
    for (int i = threadIdx.x; i < K * HID; i += blockDim.x) wlds[i] = w1[i];
    __syncthreads();
    int l = threadIdx.x & 31;
    int r = blockIdx.x * (blockDim.x >> 5) + (threadIdx.x >> 5);
    if (r >= n) return;
    const float4* rowv = (const float4*)(x + (size_t)r * K);
    float acc = 0.f;
    for (int k4 = 0; k4 < (K >> 2); k4++) {
        float4 v = rowv[k4];                        // broadcast within group
        int k = k4 << 2;
        acc = fmaf(v.x, wlds[(k + 0) * HID + l], acc);
        acc = fmaf(v.y, wlds[(k + 1) * HID + l], acc);
        acc = fmaf(v.z, wlds[(k + 2) * HID + l], acc);
        acc = fmaf(v.w, wlds[(k + 3) * HID + l], acc);
    }
    node_epilogue(acc, r, l, asrc, adst, elw, ys, yd, als, ald);
}

// block 2 prep: xp = zb @ w2 (32x32 via shfl broadcast), fused epilogue.
__global__ void k_b2prep(const float* __restrict__ zb, const float* __restrict__ w2,
                         const float* __restrict__ asrc, const float* __restrict__ adst,
                         const float* __restrict__ elw,
                         float* __restrict__ ys, float* __restrict__ yd,
                         float* __restrict__ als, float* __restrict__ ald, int n) {
    int l = threadIdx.x & 31;
    int r = blockIdx.x * (blockDim.x >> 5) + (threadIdx.x >> 5);
    if (r >= n) return;
    float zv = zb[r * HID + l];
    int gbase = threadIdx.x & 32;
    float acc = 0.f;
    #pragma unroll
    for (int k = 0; k < HID; k++) {
        float zk = __shfl(zv, gbase + k);
        acc = fmaf(zk, w2[k * HID + l], acc);
    }
    node_epilogue(acc, r, l, asrc, adst, elw, ys, yd, als, ald);
}

// One wave per node: online-softmax weighted accumulate + fused proj+BN (+pool).
template<bool POOL>
__global__ void k_gat(const int* __restrict__ offsets, const ushort_t* __restrict__ ssrc,
                      const float* __restrict__ wsum, const float* __restrict__ als,
                      const float* __restrict__ ald, const float* __restrict__ ys,
                      const float* __restrict__ yd, const float* __restrict__ elw,
                      const float* __restrict__ elb, const float* __restrict__ bvec,
                      const float* __restrict__ pw, const float* __restrict__ pb,
                      const float* __restrict__ bng, const float* __restrict__ bnb,
                      float* __restrict__ zout, float* __restrict__ pool,
                      const int* __restrict__ batch, int n) {
    int lane = threadIdx.x & 63;
    int node = blockIdx.x * (blockDim.x >> 6) + (threadIdx.x >> 6);
    if (node >= n) return;
    int beg = offsets[node], end = offsets[node + 1];
    int deg = end - beg;
    int half = lane >> 5, l = lane & 31;
    float aldi = ald[node];
    float agg;
    if (deg > 0) {
        int mid = beg + (deg >> 1);
        int e  = half ? mid : beg;
        int e1 = half ? end : mid;
        float m = -INFINITY, acc = 0.f, esum = 0.f;
        for (; e + 8 <= e1; e += 8) {
            int j0 = ssrc[e + 0], j1 = ssrc[e + 1], j2 = ssrc[e + 2], j3 = ssrc[e + 3];
            int j4 = ssrc[e + 4], j5 = ssrc[e + 5], j6 = ssrc[e + 6], j7 = ssrc[e + 7];
            float a0 = als[j0] + aldi, a1 = als[j1] + aldi, a2 = als[j2] + aldi, a3 = als[j3] + aldi;
            float a4 = als[j4] + aldi, a5 = als[j5] + aldi, a6 = als[j6] + aldi, a7 = als[j7] + aldi;
            a0 = (a0 >= 0.f) ? a0 : 0.2f * a0;  a1 = (a1 >= 0.f) ? a1 : 0.2f * a1;
            a2 = (a2 >= 0.f) ? a2 : 0.2f * a2;  a3 = (a3 >= 0.f) ? a3 : 0.2f * a3;
            a4 = (a4 >= 0.f) ? a4 : 0.2f * a4;  a5 = (a5 >= 0.f) ? a5 : 0.2f * a5;
            a6 = (a6 >= 0.f) ? a6 : 0.2f * a6;  a7 = (a7 >= 0.f) ? a7 : 0.2f * a7;
            float cmax = fmaxf(fmaxf(fmaxf(a0, a1), fmaxf(a2, a3)),
                               fmaxf(fmaxf(a4, a5), fmaxf(a6, a7)));
            if (cmax > m) { float sc = __expf(m - cmax); acc *= sc; esum *= sc; m = cmax; }
            float w0 = __expf(a0 - m), w1 = __expf(a1 - m), w2 = __expf(a2 - m), w3 = __expf(a3 - m);
            float w4 = __expf(a4 - m), w5 = __expf(a5 - m), w6 = __expf(a6 - m), w7 = __expf(a7 - m);
            acc = fmaf(w0, ys[j0 * HID + l], acc);  esum += w0;
            acc = fmaf(w1, ys[j1 * HID + l], acc);  esum += w1;
            acc = fmaf(w2, ys[j2 * HID + l], acc);  esum += w2;
            acc = fmaf(w3, ys[j3 * HID + l], acc);  esum += w3;
            acc = fmaf(w4, ys[j4 * HID + l], acc);  esum += w4;
            acc = fmaf(w5, ys[j5 * HID + l], acc);  esum += w5;
            acc = fmaf(w6, ys[j6 * HID + l], acc);  esum += w6;
            acc = fmaf(w7, ys[j7 * HID + l], acc);  esum += w7;
        }
        for (; e < e1; e++) {
            int j = ssrc[e];
            float a = als[j] + aldi;
            a = (a >= 0.f) ? a : 0.2f * a;
            if (a > m) { float sc = __expf(m - a); acc *= sc; esum *= sc; m = a; }
            float w = __expf(a - m);
            acc = fmaf(w, ys[j * HID + l], acc);
            esum += w;
        }
        // merge the two half-waves (empty half: m=-inf -> weight exp(-inf)=0)
        float mo = __shfl_xor(m, 32);
        float M  = fmaxf(m, mo);
        float c0 = __expf(m - M), c1 = __expf(mo - M);
        float se = esum * c0 + __shfl_xor(esum, 32) * c1;
        acc      = acc  * c0 + __shfl_xor(acc, 32)  * c1;
        agg = acc / se + wsum[node] * elw[64 * HID + l];
    } else {
        agg = 0.f;
    }
    agg += (float)deg * (yd[node * HID + l] + elb[l]) + bvec[l];
    // projection 32x32 via shfl broadcast, then LeakyReLU + BatchNorm(eval)
    float z = 0.f;
    #pragma unroll
    for (int k = 0; k < HID; k++) {
        float av = __shfl(agg, k);                  // agg identical on both halves
        z = fmaf(av, pw[k * HID + l], z);
    }
    z += pb[l];
    z = (z >= 0.f) ? z : 0.2f * z;
    const float inv = 0.99999500003749971875f;      // 1/sqrt(1+1e-5)
    z = fmaf(z, bng[l] * inv, bnb[l]);
    if (lane < 32) {
        if (POOL) atomicAdd(&pool[batch[node] * HID + l], z);
        else      zout[node * HID + l] = z;
    }
}

__global__ void k_head(const float* __restrict__ pool, const int* __restrict__ batch,
                       const float* __restrict__ fw, const float* __restrict__ fb,
                       float* __restrict__ out, int n, int ngraphs, int ncls) {
    __shared__ int scnt[64];
    int t = threadIdx.x;
    if (t < ngraphs) scnt[t] = 0;
    __syncthreads();
    for (int i = t; i < n; i += blockDim.x) atomicAdd(&scnt[batch[i]], 1);
    __syncthreads();
    if (t < ngraphs * ncls) {
        int g = t / ncls, c = t % ncls;
        float cc = fmaxf((float)scnt[g], 1.0f);
        float acc = 0.f;
        for (int k = 0; k < HID; k++)
            acc = fmaf(pool[g * HID + k] / cc, fw[k * ncls + c], acc);
        out[t] = acc + fb[c];
    }
}

extern "C" void kernel_launch(void* const* d_in, const int* in_sizes, int n_in,
                              void* d_out, int out_size, void* d_ws, size_t ws_size,
                              hipStream_t stream) {
    const float* x     = (const float*)d_in[0];
    const float* ea    = (const float*)d_in[1];
    const int*   eidx  = (const int*)d_in[2];
    const int*   batch = (const int*)d_in[3];
    const float* w1    = (const float*)d_in[4];
    const float* asrc1 = (const float*)d_in[5];
    const float* adst1 = (const float*)d_in[6];
    const float* b1    = (const float*)d_in[7];
    const float* elw1  = (const float*)d_in[8];
    const float* elb1  = (const float*)d_in[9];
    const float* pw1   = (const float*)d_in[10];
    const float* pb1   = (const float*)d_in[11];
    const float* bng1  = (const float*)d_in[12];
    const float* bnb1  = (const float*)d_in[13];
    const float* w2    = (const float*)d_in[14];
    const float* asrc2 = (const float*)d_in[15];
    const float* adst2 = (const float*)d_in[16];
    const float* b2    = (const float*)d_in[17];
    const float* elw2  = (const float*)d_in[18];
    const float* elb2  = (const float*)d_in[19];
    const float* pw2   = (const float*)d_in[20];
    const float* pb2   = (const float*)d_in[21];
    const float* bng2  = (const float*)d_in[22];
    const float* bnb2  = (const float*)d_in[23];
    const float* fw    = (const float*)d_in[24];
    const float* fb    = (const float*)d_in[25];

    const int E  = in_sizes[1];
    const int N  = in_sizes[3];
    const int K1 = in_sizes[4] / HID;        // 200
    const int NCLS = in_sizes[25];           // 2
    const int NG = out_size / NCLS;          // 32
    const int NBUCK = (N + BUCK_BINS - 1) / BUCK_BINS;   // 100

    float* ws = (float*)d_ws;
    size_t off = 0;
    auto alloc = [&](size_t nelem) { size_t r = off; off += nelem; return r; };
    int*      part    = (int*)(ws + alloc((size_t)NB_SORT * N));
    float*    partw   = ws + alloc((size_t)NB_SORT * N);
    // ebuf (E u32) overlays part+partw: both fully consumed before k_bscatter writes.
    uint_t*   ebuf    = (uint_t*)part;
    int*      totals  = (int*)(ws + alloc(N));
    int*      offsets = (int*)(ws + alloc(N + 1));
    float*    wsum    = ws + alloc(N);
    int*      bcur    = (int*)(ws + alloc((size_t)NB_SORT * NBUCK));
    ushort_t* ssrc    = (ushort_t*)(ws + alloc((E + 1) / 2));
    float*    ys      = ws + alloc((size_t)N * HID);
    float*    yd      = ws + alloc((size_t)N * HID);
    float*    zb      = ws + alloc((size_t)N * HID);
    float*    als     = ws + alloc(N);
    float*    ald     = ws + alloc(N);
    float*    pool    = ws + alloc((size_t)NG * HID);
    (void)ws_size; (void)n_in;

    const int chunk = (E + NB_SORT - 1) / NB_SORT;
    const int binb = (N + 255) / 256;

    // ---- counting sort of edges by dst (2-level bucket sort, no device atomics) ----
    k_part_hist<<<NB_SORT, 256, 2 * N * sizeof(int), stream>>>(
        eidx + E, ea, part, partw, E, N, chunk);
    k_reduce<<<binb, 256, 0, stream>>>(part, partw, totals, wsum, N, NB_SORT);
    k_scan_small<<<1, 1024, 0, stream>>>(totals, offsets, pool, N, NG * HID);
    k_bcur<<<NBUCK, 64, 0, stream>>>(part, offsets, bcur, N, NB_SORT, NBUCK);
    k_bscatter<<<NB_SORT, 256, NBUCK * sizeof(int), stream>>>(
        eidx, eidx + E, bcur, ebuf, E, NBUCK, chunk);
    k_bsort<<<NBUCK, 256, BSORT_CAP * sizeof(ushort_t), stream>>>(
        ebuf, offsets, ssrc, N, NBUCK);

    int gb8 = (N + 7) / 8;

    // ---- block 1 ----
    k_b1prep<<<gb8, 256, K1 * HID * sizeof(float), stream>>>(
        x, w1, asrc1, adst1, elw1, ys, yd, als, ald, N, K1);
    k_gat<false><<<(N + 3) / 4, 256, 0, stream>>>(offsets, ssrc, wsum, als, ald, ys, yd,
        elw1, elb1, b1, pw1, pb1, bng1, bnb1, zb, nullptr, batch, N);

    // ---- block 2 (pool fused into gat epilogue) ----
    k_b2prep<<<gb8, 256, 0, stream>>>(zb, w2, asrc2, adst2, elw2, ys, yd, als, ald, N);
    k_gat<true><<<(N + 3) / 4, 256, 0, stream>>>(offsets, ssrc, wsum, als, ald, ys, yd,
        elw2, elb2, b2, pw2, pb2, bng2, bnb2, nullptr, pool, batch, N);

    // ---- head (computes per-graph counts itself) ----
    k_head<<<1, 256, 0, stream>>>(pool, batch, fw, fb, (float*)d_out, N, NG, NCLS);
}

// Round 7
// 240.435 us; speedup vs baseline: 1.1049x; 1.1049x over previous
//
#include <hip/hip_runtime.h>
#include <hip/hip_bf16.h>

// GAT_51788715655952. Counting sort of edges by dst via 2-level bucket sort with
// all cross-block reductions done bin/bucket-parallel and coalesced (round-4/6
// lesson: any serial walk over the 128-wide partial matrix = 60-800us latency
// chain). Per-node wave then does online-softmax weighted sum of ys[src];
// edge-linear decomposed:
//   agg[i] = deg*(yd[i]+elb) + (sum w_e*ys[src_e])/sum w_e + wsum[i]*elw[64] + b
// Block-2 prep (xp2 = z1 @ w2 + epilogue) fused into gat1's tail.

#define HID 32
#define NB_SORT 128
#define BUCK_SHIFT 6
#define BUCK_BINS 64
#define BSORT_CAP 20480   // ushort staging entries (40KB LDS); mean bucket ~12.8K

typedef unsigned short ushort_t;
typedef unsigned int uint_t;

// per-block LDS histogram: counts + sum|ea| per dst bin -> partials; plus
// bucket-level counts bpart[b][g] reduced from the same LDS histogram.
__global__ void k_part_hist(const int* __restrict__ dst, const float* __restrict__ ea,
                            int* __restrict__ part, float* __restrict__ partw,
                            int* __restrict__ bpart,
                            int E, int nbins, int nbuck, int chunk) {
    extern __shared__ int lds[];                   // nbins ints + nbins floats
    int* hc = lds;
    float* hw = (float*)(lds + nbins);
    for (int i = threadIdx.x; i < nbins; i += blockDim.x) { hc[i] = 0; hw[i] = 0.f; }
    __syncthreads();
    int b = blockIdx.x;
    int lo = b * chunk, hi = min(lo + chunk, E);
    for (int e = lo + threadIdx.x; e < hi; e += blockDim.x) {
        int d = dst[e];
        atomicAdd(&hc[d], 1);                      // LDS atomic
        atomicAdd(&hw[d], fabsf(ea[e]));           // LDS atomic
    }
    __syncthreads();
    for (int i = threadIdx.x; i < nbins; i += blockDim.x) {
        part[b * nbins + i]  = hc[i];
        partw[b * nbins + i] = hw[i];
    }
    for (int g = threadIdx.x; g < nbuck; g += blockDim.x) {
        int s = 0;
        int base = g << BUCK_SHIFT;
        int nb_ = min(BUCK_BINS, nbins - base);
        for (int k = 0; k < nb_; k++) s += hc[base + k];
        bpart[b * nbuck + g] = s;                  // 400B coalesced row
    }
}

// bin-parallel column reduce: totals[i] = sum_b part[b][i]; wsum[i] = sum_b partw[b][i].
__global__ void k_reduce(const int* __restrict__ part, const float* __restrict__ partw,
                         int* __restrict__ totals, float* __restrict__ wsum,
                         int nbins, int nb) {
    int i = blockIdx.x * blockDim.x + threadIdx.x;
    if (i >= nbins) return;
    int t = 0; float w = 0.f;
    for (int b = 0; b < nb; b++) {
        t += part[b * nbins + i];
        w += partw[b * nbins + i];
    }
    totals[i] = t;
    wsum[i] = w;
}

// single block: exclusive scan of totals -> offsets; zero pool; then bucket-level
// column scan of bpart -> per-(block,bucket) start cursors bcur (coalesced 400B rows).
__global__ void k_scan_small(const int* __restrict__ totals, int* __restrict__ offsets,
                             float* __restrict__ pool, const int* __restrict__ bpart,
                             int* __restrict__ bcur, int nbins, int nb, int nbuck,
                             int poolN) {
    __shared__ int wtot[16];
    __shared__ int sbase[128];                     // bucket base offsets
    int t = threadIdx.x;
    int chunk = (nbins + 1023) / 1024;
    int lo = t * chunk, hi = min(lo + chunk, nbins);
    int s = 0;
    for (int i = lo; i < hi; i++) s += totals[i];
    int lane = t & 63, wid = t >> 6;
    int v = s;
    for (int d = 1; d < 64; d <<= 1) { int u = __shfl_up(v, d); if (lane >= d) v += u; }
    if (lane == 63) wtot[wid] = v;
    __syncthreads();
    if (wid == 0) {
        int w = (lane < 16) ? wtot[lane] : 0;
        for (int d = 1; d < 16; d <<= 1) { int u = __shfl_up(w, d); if (lane >= d) w += u; }
        if (lane < 16) wtot[lane] = w;
    }
    __syncthreads();
    int run = (wid > 0 ? wtot[wid - 1] : 0) + (v - s);   // exclusive prefix
    for (int i = lo; i < hi; i++) {
        offsets[i] = run;
        if ((i & (BUCK_BINS - 1)) == 0) sbase[i >> BUCK_SHIFT] = run;
        run += totals[i];
    }
    if (lo < nbins && hi == nbins) offsets[nbins] = run;
    if (t < poolN) pool[t] = 0.f;
    __syncthreads();
    if (t < nbuck) {                               // 128 coalesced iterations
        int c = sbase[t];
        for (int b = 0; b < nb; b++) {
            int p = bpart[b * nbuck + t];
            bcur[b * nbuck + t] = c;
            c += p;
        }
    }
}

// phase-1 scatter: packed (dst<<16)|src into bucket regions (LDS bucket cursors).
__global__ void k_bscatter(const int* __restrict__ src, const int* __restrict__ dst,
                           const int* __restrict__ bcur, uint_t* __restrict__ ebuf,
                           int E, int nbuck, int chunk) {
    extern __shared__ int cur[];                   // nbuck ints
    int b = blockIdx.x;
    for (int i = threadIdx.x; i < nbuck; i += blockDim.x) cur[i] = bcur[b * nbuck + i];
    __syncthreads();
    int lo = b * chunk, hi = min(lo + chunk, E);
    for (int e = lo + threadIdx.x; e < hi; e += blockDim.x) {
        int d = dst[e];
        int p = atomicAdd(&cur[d >> BUCK_SHIFT], 1);   // LDS atomic
        ebuf[p] = ((uint_t)d << 16) | (uint_t)src[e];
    }
}

// phase-2: per-bucket LDS counting sort; ssrc written fully contiguous.
__global__ void k_bsort(const uint_t* __restrict__ ebuf, const int* __restrict__ offsets,
                        ushort_t* __restrict__ ssrc, int nbins, int nbuck) {
    __shared__ int hist[BUCK_BINS];
    __shared__ int cur[BUCK_BINS];
    extern __shared__ ushort_t sbuf[];             // BSORT_CAP entries
    int g = blockIdx.x;
    if (g >= nbuck) return;
    int binlo = g << BUCK_SHIFT;
    int nbin = min(BUCK_BINS, nbins - binlo);
    int base = offsets[binlo];
    int cnt = offsets[binlo + nbin] - base;
    int t = threadIdx.x;
    if (t < BUCK_BINS) hist[t] = 0;
    __syncthreads();
    for (int i = t; i < cnt; i += blockDim.x) {
        int dl = (int)(ebuf[base + i] >> 16) - binlo;
        atomicAdd(&hist[dl], 1);
    }
    __syncthreads();
    if (t < BUCK_BINS) {                           // wave 0: exclusive scan of 64 bins
        int v = hist[t];
        int p = v;
        #pragma unroll
        for (int d = 1; d < 64; d <<= 1) { int u = __shfl_up(p, d); if (t >= d) p += u; }
        cur[t] = p - v;
    }
    __syncthreads();
    if (cnt <= BSORT_CAP) {
        for (int i = t; i < cnt; i += blockDim.x) {
            uint_t v = ebuf[base + i];
            int dl = (int)(v >> 16) - binlo;
            int p = atomicAdd(&cur[dl], 1);        // LDS atomic
            sbuf[p] = (ushort_t)(v & 0xFFFFu);     // LDS staging
        }
        __syncthreads();
        for (int i = t; i < cnt; i += blockDim.x)  // coalesced contiguous write
            ssrc[base + i] = sbuf[i];
    } else {                                       // fallback (never expected)
        for (int i = t; i < cnt; i += blockDim.x) {
            uint_t v = ebuf[base + i];
            int dl = (int)(v >> 16) - binlo;
            int p = atomicAdd(&cur[dl], 1);
            ssrc[base + p] = (ushort_t)(v & 0xFFFFu);
        }
    }
}

// shared epilogue: given xp (lane l of a 32-lane group holds xp[row][l]), compute
// als/ald (group reduce) and ys/yd (group broadcast matmul vs elw).
__device__ __forceinline__ void node_epilogue(float xp, int r, int l,
        const float* __restrict__ asrc, const float* __restrict__ adst,
        const float* __restrict__ elw,
        float* __restrict__ ys, float* __restrict__ yd,
        float* __restrict__ als, float* __restrict__ ald) {
    float ps = xp * asrc[l], pd = xp * adst[l];
    #pragma unroll
    for (int mask = 16; mask >= 1; mask >>= 1) {
        ps += __shfl_xor(ps, mask);
        pd += __shfl_xor(pd, mask);
    }
    if (l == 0) { als[r] = ps; ald[r] = pd; }
    int gbase = threadIdx.x & 32;   // group base lane within the 64-wide wave
    float yss = 0.f, ydd = 0.f;
    #pragma unroll
    for (int k = 0; k < HID; k++) {
        float xk = __shfl(xp, gbase + k);
        yss = fmaf(xk, elw[(HID + k) * HID + l], yss);
        ydd = fmaf(xk, elw[k * HID + l], ydd);
    }
    ys[r * HID + l] = yss;
    yd[r * HID + l] = ydd;
}

// block 1 prep: xp = x @ w1 (K=200, w1 staged in LDS), fused epilogue.
__global__ void k_b1prep(const float* __restrict__ x, const float* __restrict__ w1,
                         const float* __restrict__ asrc, const float* __restrict__ adst,
                         const float* __restrict__ elw,
                         float* __restrict__ ys, float* __restrict__ yd,
                         float* __restrict__ als, float* __restrict__ ald,
                         int n, int K) {
    extern __shared__ float wlds[];                 // K*32 floats
    for (int i = threadIdx.x; i < K * HID; i += blockDim.x) wlds[i] = w1[i];
    __syncthreads();
    int l = threadIdx.x & 31;
    int r = blockIdx.x * (blockDim.x >> 5) + (threadIdx.x >> 5);
    if (r >= n) return;
    const float4* rowv = (const float4*)(x + (size_t)r * K);
    float acc = 0.f;
    for (int k4 = 0; k4 < (K >> 2); k4++) {
        float4 v = rowv[k4];                        // broadcast within group
        int k = k4 << 2;
        acc = fmaf(v.x, wlds[(k + 0) * HID + l], acc);
        acc = fmaf(v.y, wlds[(k + 1) * HID + l], acc);
        acc = fmaf(v.z, wlds[(k + 2) * HID + l], acc);
        acc = fmaf(v.w, wlds[(k + 3) * HID + l], acc);
    }
    node_epilogue(acc, r, l, asrc, adst, elw, ys, yd, als, ald);
}

// shared gat body: returns z[node][l] (identical on both half-waves).
__device__ __forceinline__ float gat_node_z(int node, int lane,
        const int* __restrict__ offsets, const ushort_t* __restrict__ ssrc,
        const float* __restrict__ wsum, const float* __restrict__ als,
        const float* __restrict__ ald, const float* __restrict__ ys,
        const float* __restrict__ yd, const float* __restrict__ elw,
        const float* __restrict__ elb, const float* __restrict__ bvec,
        const float* __restrict__ pw, const float* __restrict__ pb,
        const float* __restrict__ bng, const float* __restrict__ bnb) {
    int beg = offsets[node], end = offsets[node + 1];
    int deg = end - beg;
    int half = lane >> 5, l = lane & 31;
    float aldi = ald[node];
    float agg;
    if (deg > 0) {
        int mid = beg + (deg >> 1);
        int e  = half ? mid : beg;
        int e1 = half ? end : mid;
        float m = -INFINITY, acc = 0.f, esum = 0.f;
        for (; e + 8 <= e1; e += 8) {
            int j0 = ssrc[e + 0], j1 = ssrc[e + 1], j2 = ssrc[e + 2], j3 = ssrc[e + 3];
            int j4 = ssrc[e + 4], j5 = ssrc[e + 5], j6 = ssrc[e + 6], j7 = ssrc[e + 7];
            float a0 = als[j0] + aldi, a1 = als[j1] + aldi, a2 = als[j2] + aldi, a3 = als[j3] + aldi;
            float a4 = als[j4] + aldi, a5 = als[j5] + aldi, a6 = als[j6] + aldi, a7 = als[j7] + aldi;
            a0 = (a0 >= 0.f) ? a0 : 0.2f * a0;  a1 = (a1 >= 0.f) ? a1 : 0.2f * a1;
            a2 = (a2 >= 0.f) ? a2 : 0.2f * a2;  a3 = (a3 >= 0.f) ? a3 : 0.2f * a3;
            a4 = (a4 >= 0.f) ? a4 : 0.2f * a4;  a5 = (a5 >= 0.f) ? a5 : 0.2f * a5;
            a6 = (a6 >= 0.f) ? a6 : 0.2f * a6;  a7 = (a7 >= 0.f) ? a7 : 0.2f * a7;
            float cmax = fmaxf(fmaxf(fmaxf(a0, a1), fmaxf(a2, a3)),
                               fmaxf(fmaxf(a4, a5), fmaxf(a6, a7)));
            if (cmax > m) { float sc = __expf(m - cmax); acc *= sc; esum *= sc; m = cmax; }
            float w0 = __expf(a0 - m), w1 = __expf(a1 - m), w2 = __expf(a2 - m), w3 = __expf(a3 - m);
            float w4 = __expf(a4 - m), w5 = __expf(a5 - m), w6 = __expf(a6 - m), w7 = __expf(a7 - m);
            acc = fmaf(w0, ys[j0 * HID + l], acc);  esum += w0;
            acc = fmaf(w1, ys[j1 * HID + l], acc);  esum += w1;
            acc = fmaf(w2, ys[j2 * HID + l], acc);  esum += w2;
            acc = fmaf(w3, ys[j3 * HID + l], acc);  esum += w3;
            acc = fmaf(w4, ys[j4 * HID + l], acc);  esum += w4;
            acc = fmaf(w5, ys[j5 * HID + l], acc);  esum += w5;
            acc = fmaf(w6, ys[j6 * HID + l], acc);  esum += w6;
            acc = fmaf(w7, ys[j7 * HID + l], acc);  esum += w7;
        }
        for (; e < e1; e++) {
            int j = ssrc[e];
            float a = als[j] + aldi;
            a = (a >= 0.f) ? a : 0.2f * a;
            if (a > m) { float sc = __expf(m - a); acc *= sc; esum *= sc; m = a; }
            float w = __expf(a - m);
            acc = fmaf(w, ys[j * HID + l], acc);
            esum += w;
        }
        // merge the two half-waves (empty half: m=-inf -> weight exp(-inf)=0)
        float mo = __shfl_xor(m, 32);
        float M  = fmaxf(m, mo);
        float c0 = __expf(m - M), c1 = __expf(mo - M);
        float se = esum * c0 + __shfl_xor(esum, 32) * c1;
        acc      = acc  * c0 + __shfl_xor(acc, 32)  * c1;
        agg = acc / se + wsum[node] * elw[64 * HID + l];
    } else {
        agg = 0.f;
    }
    agg += (float)deg * (yd[node * HID + l] + elb[l]) + bvec[l];
    // projection 32x32 via shfl broadcast, then LeakyReLU + BatchNorm(eval)
    float z = 0.f;
    #pragma unroll
    for (int k = 0; k < HID; k++) {
        float av = __shfl(agg, k);                  // agg identical on both halves
        z = fmaf(av, pw[k * HID + l], z);
    }
    z += pb[l];
    z = (z >= 0.f) ? z : 0.2f * z;
    const float inv = 0.99999500003749971875f;      // 1/sqrt(1+1e-5)
    return fmaf(z, bng[l] * inv, bnb[l]);
}

// gat block 1, with block-2 prep (xp2 = z @ w2 + epilogue) fused into the tail.
__global__ void k_gat1(const int* __restrict__ offsets, const ushort_t* __restrict__ ssrc,
                       const float* __restrict__ wsum, const float* __restrict__ als,
                       const float* __restrict__ ald, const float* __restrict__ ys,
                       const float* __restrict__ yd, const float* __restrict__ elw,
                       const float* __restrict__ elb, const float* __restrict__ bvec,
                       const float* __restrict__ pw, const float* __restrict__ pb,
                       const float* __restrict__ bng, const float* __restrict__ bnb,
                       const float* __restrict__ w2, const float* __restrict__ asrc2,
                       const float* __restrict__ adst2, const float* __restrict__ elw2,
                       float* __restrict__ ys2, float* __restrict__ yd2,
                       float* __restrict__ als2, float* __restrict__ ald2, int n) {
    int lane = threadIdx.x & 63;
    int node = blockIdx.x * (blockDim.x >> 6) + (threadIdx.x >> 6);
    if (node >= n) return;
    float z = gat_node_z(node, lane, offsets, ssrc, wsum, als, ald, ys, yd,
                         elw, elb, bvec, pw, pb, bng, bnb);
    // xp2 = z @ w2 (32x32 via shfl broadcast), both halves redundantly
    int l = lane & 31, gbase = threadIdx.x & 32;
    float acc = 0.f;
    #pragma unroll
    for (int k = 0; k < HID; k++) {
        float zk = __shfl(z, gbase + k);
        acc = fmaf(zk, w2[k * HID + l], acc);
    }
    node_epilogue(acc, node, l, asrc2, adst2, elw2, ys2, yd2, als2, ald2);
}

// gat block 2: epilogue pools directly.
__global__ void k_gat2(const int* __restrict__ offsets, const ushort_t* __restrict__ ssrc,
                       const float* __restrict__ wsum, const float* __restrict__ als,
                       const float* __restrict__ ald, const float* __restrict__ ys,
                       const float* __restrict__ yd, const float* __restrict__ elw,
                       const float* __restrict__ elb, const float* __restrict__ bvec,
                       const float* __restrict__ pw, const float* __restrict__ pb,
                       const float* __restrict__ bng, const float* __restrict__ bnb,
                       float* __restrict__ pool, const int* __restrict__ batch, int n) {
    int lane = threadIdx.x & 63;
    int node = blockIdx.x * (blockDim.x >> 6) + (threadIdx.x >> 6);
    if (node >= n) return;
    float z = gat_node_z(node, lane, offsets, ssrc, wsum, als, ald, ys, yd,
                         elw, elb, bvec, pw, pb, bng, bnb);
    if (lane < 32) atomicAdd(&pool[batch[node] * HID + lane], z);
}

__global__ void k_head(const float* __restrict__ pool, const int* __restrict__ batch,
                       const float* __restrict__ fw, const float* __restrict__ fb,
                       float* __restrict__ out, int n, int ngraphs, int ncls) {
    __shared__ int scnt[64];
    int t = threadIdx.x;
    if (t < ngraphs) scnt[t] = 0;
    __syncthreads();
    for (int i = t; i < n; i += blockDim.x) atomicAdd(&scnt[batch[i]], 1);
    __syncthreads();
    if (t < ngraphs * ncls) {
        int g = t / ncls, c = t % ncls;
        float cc = fmaxf((float)scnt[g], 1.0f);
        float acc = 0.f;
        for (int k = 0; k < HID; k++)
            acc = fmaf(pool[g * HID + k] / cc, fw[k * ncls + c], acc);
        out[t] = acc + fb[c];
    }
}

extern "C" void kernel_launch(void* const* d_in, const int* in_sizes, int n_in,
                              void* d_out, int out_size, void* d_ws, size_t ws_size,
                              hipStream_t stream) {
    const float* x     = (const float*)d_in[0];
    const float* ea    = (const float*)d_in[1];
    const int*   eidx  = (const int*)d_in[2];
    const int*   batch = (const int*)d_in[3];
    const float* w1    = (const float*)d_in[4];
    const float* asrc1 = (const float*)d_in[5];
    const float* adst1 = (const float*)d_in[6];
    const float* b1    = (const float*)d_in[7];
    const float* elw1  = (const float*)d_in[8];
    const float* elb1  = (const float*)d_in[9];
    const float* pw1   = (const float*)d_in[10];
    const float* pb1   = (const float*)d_in[11];
    const float* bng1  = (const float*)d_in[12];
    const float* bnb1  = (const float*)d_in[13];
    const float* w2    = (const float*)d_in[14];
    const float* asrc2 = (const float*)d_in[15];
    const float* adst2 = (const float*)d_in[16];
    const float* b2    = (const float*)d_in[17];
    const float* elw2  = (const float*)d_in[18];
    const float* elb2  = (const float*)d_in[19];
    const float* pw2   = (const float*)d_in[20];
    const float* pb2   = (const float*)d_in[21];
    const float* bng2  = (const float*)d_in[22];
    const float* bnb2  = (const float*)d_in[23];
    const float* fw    = (const float*)d_in[24];
    const float* fb    = (const float*)d_in[25];

    const int E  = in_sizes[1];
    const int N  = in_sizes[3];
    const int K1 = in_sizes[4] / HID;        // 200
    const int NCLS = in_sizes[25];           // 2
    const int NG = out_size / NCLS;          // 32
    const int NBUCK = (N + BUCK_BINS - 1) / BUCK_BINS;   // 100

    float* ws = (float*)d_ws;
    size_t off = 0;
    auto alloc = [&](size_t nelem) { size_t r = off; off += nelem; return r; };
    int*      part    = (int*)(ws + alloc((size_t)NB_SORT * N));
    float*    partw   = ws + alloc((size_t)NB_SORT * N);
    // ebuf (E u32) overlays part: part fully consumed (k_reduce) before k_bscatter.
    uint_t*   ebuf    = (uint_t*)part;
    int*      bpart   = (int*)(ws + alloc((size_t)NB_SORT * NBUCK));
    int*      bcur    = (int*)(ws + alloc((size_t)NB_SORT * NBUCK));
    int*      totals  = (int*)(ws + alloc(N));
    int*      offsets = (int*)(ws + alloc(N + 1));
    float*    wsum    = ws + alloc(N);
    ushort_t* ssrc    = (ushort_t*)(ws + alloc((E + 1) / 2));
    float*    ys_a    = ws + alloc((size_t)N * HID);
    float*    yd_a    = ws + alloc((size_t)N * HID);
    float*    ys_b    = ws + alloc((size_t)N * HID);
    float*    yd_b    = ws + alloc((size_t)N * HID);
    float*    als_a   = ws + alloc(N);
    float*    ald_a   = ws + alloc(N);
    float*    als_b   = ws + alloc(N);
    float*    ald_b   = ws + alloc(N);
    float*    pool    = ws + alloc((size_t)NG * HID);
    (void)ws_size; (void)n_in;

    const int chunk = (E + NB_SORT - 1) / NB_SORT;
    const int binb = (N + 255) / 256;

    // ---- counting sort of edges by dst (2-level bucket sort, no device atomics) ----
    k_part_hist<<<NB_SORT, 256, 2 * N * sizeof(int), stream>>>(
        eidx + E, ea, part, partw, bpart, E, N, NBUCK, chunk);
    k_reduce<<<binb, 256, 0, stream>>>(part, partw, totals, wsum, N, NB_SORT);
    k_scan_small<<<1, 1024, 0, stream>>>(totals, offsets, pool, bpart, bcur,
                                         N, NB_SORT, NBUCK, NG * HID);
    k_bscatter<<<NB_SORT, 256, NBUCK * sizeof(int), stream>>>(
        eidx, eidx + E, bcur, ebuf, E, NBUCK, chunk);
    k_bsort<<<NBUCK, 256, BSORT_CAP * sizeof(ushort_t), stream>>>(
        ebuf, offsets, ssrc, N, NBUCK);

    // ---- block 1 prep ----
    k_b1prep<<<(N + 7) / 8, 256, K1 * HID * sizeof(float), stream>>>(
        x, w1, asrc1, adst1, elw1, ys_a, yd_a, als_a, ald_a, N, K1);

    // ---- gat block 1 (block-2 prep fused) ----
    k_gat1<<<(N + 3) / 4, 256, 0, stream>>>(offsets, ssrc, wsum, als_a, ald_a, ys_a, yd_a,
        elw1, elb1, b1, pw1, pb1, bng1, bnb1,
        w2, asrc2, adst2, elw2, ys_b, yd_b, als_b, ald_b, N);

    // ---- gat block 2 (pool fused) ----
    k_gat2<<<(N + 3) / 4, 256, 0, stream>>>(offsets, ssrc, wsum, als_b, ald_b, ys_b, yd_b,
        elw2, elb2, b2, pw2, pb2, bng2, bnb2, pool, batch, N);

    // ---- head (computes per-graph counts itself) ----
    k_head<<<1, 256, 0, stream>>>(pool, batch, fw, fb, (float*)d_out, N, NG, NCLS);
}